// Round 8
// baseline (7205.792 us; speedup 1.0000x reference)
//
#include <hip/hip_runtime.h>

typedef _Float16 f16;
typedef _Float16 half8 __attribute__((ext_vector_type(8)));
typedef float f32x4 __attribute__((ext_vector_type(4)));
typedef float f32x2 __attribute__((ext_vector_type(2)));

#define TT 512
#define HID 1024

__device__ __forceinline__ half8 cvt8(f32x4 lo, f32x4 hi) {
  half8 r;
  r[0]=(f16)lo[0]; r[1]=(f16)lo[1]; r[2]=(f16)lo[2]; r[3]=(f16)lo[3];
  r[4]=(f16)hi[0]; r[5]=(f16)hi[1]; r[6]=(f16)hi[2]; r[7]=(f16)hi[3];
  return r;
}
// device-scope coherent ops: write through / read past L2 (never flush caches)
__device__ __forceinline__ void st_sc_u32(unsigned* p, unsigned v) {
  asm volatile("global_store_dword %0, %1, off sc0 sc1" :: "v"(p), "v"(v) : "memory");
}
__device__ __forceinline__ unsigned ld_sc_u32(const unsigned* p) {
  unsigned v;
  asm volatile("global_load_dword %0, %1, off sc0 sc1\n\ts_waitcnt vmcnt(0)"
               : "=v"(v) : "v"(p) : "memory");
  return v;
}
__device__ __forceinline__ void atom_inc_sc(unsigned* p) {
  unsigned one = 1u;
  asm volatile("global_atomic_add %0, %1, off sc1" :: "v"(p), "v"(one) : "memory");
}
__device__ __forceinline__ float sigm(float x)  { return 1.f/(1.f + __expf(-x)); }
__device__ __forceinline__ float ftanh(float x) { return 1.f - 2.f/(1.f + __expf(2.f*x)); }

// x [B][T][D] f32 -> xh [T][64 seg][64 b][16 c] f16 (WG-major plane layout)
__global__ void init_misc(const float* __restrict__ x, f16* __restrict__ xh) {
  size_t idx = (size_t)blockIdx.x*256 + threadIdx.x;
  size_t i = idx*8;
  int d = (int)(i & 1023);
  size_t bt = i >> 10;
  int t = (int)(bt & 511), b = (int)(bt >> 9);
  f32x4 a = *(const f32x4*)(x+i);
  f32x4 c4 = *(const f32x4*)(x+i+4);
  int s = d >> 4, c = d & 15;
  *(half8*)(xh + (((size_t)t*64 + s)*64 + b)*16 + c) = cvt8(a,c4);
}

// Persistent pipelined TSGRU. 256 WGs x 512 thr (8 waves). WG = (layer, 16 cols),
// layer -> XCD pair {2l,2l+1}. Wave wv holds BOTH GEMMs' weights for K-chunk
// [wv*128,(wv+1)*128): bW[2][3][4] = 96 VGPRs, persistent.
// ONE sync region/step: wave0 polls upstream[t], wave1 polls own[t-1] (counting
// flags, >=8 per WG), one barrier releases (arrival implies t-1 fully done ->
// PART safe). Merged phase: r/z partials of gx+gh share accumulators; 96 MFMAs;
// one dump (4 slices/wave); one reduce+gate; per-wave drain + atomic flag.
__global__ __launch_bounds__(512, 2) void tsgru_k(
    const float* __restrict__ dtp, const float* __restrict__ Wih,
    const float* __restrict__ Whh, const float* __restrict__ bih,
    const float* __restrict__ bhh, const float* __restrict__ tau,
    const f16* __restrict__ xh, f16* __restrict__ H, f16* __restrict__ HD,
    unsigned* __restrict__ flags, float* __restrict__ out) {
  extern __shared__ char lds[];
  float* PART  = (float*)lds;              // [8 wv][4 slice][1088] f32 = 139264 B
  float* biasS = (float*)(lds + 139264);   // [6][16] f32

  const int tid = threadIdx.x, lane = tid & 63, wv = tid >> 6;
  const int bid = blockIdx.x;
  const int layer = (bid & 7) >> 1;                 // layer -> XCD pair
  const int wgl = (bid >> 3) | ((bid & 1) << 5);
  const int col0 = wgl * 16;
  const int u = (lane >> 4) & 3;

  // ---- persistent weights in VGPRs: both GEMMs, this wave's 128-K chunk
  const float* WihL = Wih + (size_t)layer*3072*HID;
  const float* WhhL = Whh + (size_t)layer*3072*HID;
  const int wcol = col0 + (lane & 15);
  half8 bW[2][3][4];
  #pragma unroll
  for (int g=0;g<2;g++)
    #pragma unroll
    for (int q=0;q<3;q++)
      #pragma unroll
      for (int ks=0;ks<4;ks++) {
        const float* p = (g ? WhhL : WihL) + (size_t)(q*HID + wcol)*HID + wv*128 + ks*32 + u*8;
        bW[g][q][ks] = cvt8(*(const f32x4*)p, *(const f32x4*)(p+4));
      }

  // ---- biases -> LDS (keep VGPR pressure down); nitau in regs
  if (tid < 96) {
    int j = tid >> 4, c = tid & 15;
    biasS[tid] = (j < 3) ? bih[layer*3072 + j*HID + col0 + c]
                         : bhh[layer*3072 + (j-3)*HID + col0 + c];
  }
  const int gb = tid >> 3, gc2 = (tid & 7)*2;
  const float ni0 = -1.f/log1pf(expf(tau[layer*HID + col0 + gc2]));
  const float ni1 = -1.f/log1pf(expf(tau[layer*HID + col0 + gc2 + 1]));
  __syncthreads();

  // A-fragment offset in a WG-major plane [seg][b][16]
  const int baseA = (wv*8 + (u>>1))*1024 + (lane&15)*16 + (u&1)*8;
  const f16* gxBase = (layer==0) ? xh : H + (size_t)(layer-1)*TT*65536;
  f16* HDl = HD + (size_t)layer*32*65536;           // 32-plane rotation
  unsigned* flagOwn = flags + (size_t)layer*TT*64;
  const unsigned* flagUp = flags + (size_t)(layer>0 ? layer-1 : 0)*TT*64;

  float hdv0 = 0.f, hdv1 = 0.f;

  for (int t = 0; t < TT; ++t) {
    const float dtg1 = (t < TT-1) ? dtp[gb*TT + t + 1] : 0.f;

    // ---- single sync region: two waves poll concurrently, barrier releases
    if (wv == 0 && layer > 0) {
      int gd = 0;
      while (!__all(ld_sc_u32(flagUp + (size_t)t*64 + lane) >= 8u)) { if (++gd > (1<<20)) break; }
    }
    if (wv == 1 && t > 0) {
      int gd = 0;
      while (!__all(ld_sc_u32(flagOwn + (size_t)(t-1)*64 + lane) >= 8u)) { if (++gd > (1<<20)) break; }
    }
    __builtin_amdgcn_s_barrier();   // deps ready; arrival also proves PART free

    const f16* gxP = gxBase + (size_t)t*65536;
    const f16* ghP = HDl + (size_t)(t & 31)*65536;

    // ---- issue all front-window A-loads together (one LLC RT covers both)
    half8 ax[2][4], ah[2][4];
    #pragma unroll
    for (int ks=0;ks<2;ks++)
      #pragma unroll
      for (int m=0;m<4;m++)
        ax[ks][m] = *(const half8*)(gxP + baseA + ks*2048 + m*256);
    if (t > 0) {
      #pragma unroll
      for (int ks=0;ks<2;ks++)
        #pragma unroll
        for (int m=0;m<4;m++)
          ah[ks][m] = *(const half8*)(ghP + baseA + ks*2048 + m*256);
    }

    f32x4 acc[4][4];   // s0=r(x+h) s1=z(x+h) s2=n_x s3=n_h
    #pragma unroll
    for (int m=0;m<4;m++) {
      acc[m][0]=(f32x4){0.f,0.f,0.f,0.f}; acc[m][1]=acc[m][0];
      acc[m][2]=acc[m][0]; acc[m][3]=acc[m][0];
    }

    // ---- gx: 48 MFMAs, window-2 roll
    #pragma unroll
    for (int ks=0;ks<4;ks++) {
      #pragma unroll
      for (int m=0;m<4;m++) {
        const half8 a = ax[ks&1][m];
        acc[m][0] = __builtin_amdgcn_mfma_f32_16x16x32_f16(a, bW[0][0][ks], acc[m][0],0,0,0);
        acc[m][1] = __builtin_amdgcn_mfma_f32_16x16x32_f16(a, bW[0][1][ks], acc[m][1],0,0,0);
        acc[m][2] = __builtin_amdgcn_mfma_f32_16x16x32_f16(a, bW[0][2][ks], acc[m][2],0,0,0);
      }
      if (ks < 2) {
        #pragma unroll
        for (int m=0;m<4;m++)
          ax[ks&1][m] = *(const half8*)(gxP + baseA + (ks+2)*2048 + m*256);
      }
    }
    // ---- gh: 48 MFMAs (r/z into SAME accumulators), window-2 roll
    if (t > 0) {
      #pragma unroll
      for (int ks=0;ks<4;ks++) {
        #pragma unroll
        for (int m=0;m<4;m++) {
          const half8 a = ah[ks&1][m];
          acc[m][0] = __builtin_amdgcn_mfma_f32_16x16x32_f16(a, bW[1][0][ks], acc[m][0],0,0,0);
          acc[m][1] = __builtin_amdgcn_mfma_f32_16x16x32_f16(a, bW[1][1][ks], acc[m][1],0,0,0);
          acc[m][3] = __builtin_amdgcn_mfma_f32_16x16x32_f16(a, bW[1][2][ks], acc[m][3],0,0,0);
        }
        if (ks < 2) {
          #pragma unroll
          for (int m=0;m<4;m++)
            ah[ks&1][m] = *(const half8*)(ghP + baseA + (ks+2)*2048 + m*256);
        }
      }
    }

    // ---- one dump: 4 slices/wave, col-major pad-68 (b128 at bank floor)
    {
      float* Pb = PART + (size_t)(wv*4)*1088 + (lane&15)*68 + u*4;
      #pragma unroll
      for (int s=0;s<4;s++)
        #pragma unroll
        for (int m=0;m<4;m++)
          *(f32x4*)(Pb + s*1088 + m*16) = acc[m][s];
    }
    asm volatile("s_waitcnt lgkmcnt(0)" ::: "memory");
    __builtin_amdgcn_s_barrier();   // PART published

    // ---- reduce + gate: thread -> (batch gb, cols gc2,gc2+1)
    {
      float hv[2];
      #pragma unroll
      for (int e=0;e<2;e++) {
        const int pb = (gc2+e)*68 + gb;
        float S0=0.f,S1=0.f,S2=0.f,S3=0.f;
        #pragma unroll
        for (int w8=0;w8<8;w8++) {
          const float* P = PART + (size_t)(w8*4)*1088 + pb;
          S0 += P[0]; S1 += P[1088]; S2 += P[2176]; S3 += P[3264];
        }
        const float hdv = e ? hdv1 : hdv0;
        const float r = sigm(S0 + biasS[gc2+e]    + biasS[48+gc2+e]);
        const float z = sigm(S1 + biasS[16+gc2+e] + biasS[64+gc2+e]);
        const float n = ftanh(S2 + biasS[32+gc2+e] + r*(S3 + biasS[80+gc2+e]));
        hv[e] = (1.f - z)*n + z*hdv;
      }
      union { f16 h[2]; unsigned uu; } pk;
      const size_t slot = (size_t)(wgl*64 + gb)*16 + gc2;
      if (layer < 3) {
        pk.h[0]=(f16)hv[0]; pk.h[1]=(f16)hv[1];
        st_sc_u32((unsigned*)(H + ((size_t)layer*TT + t)*65536 + slot), pk.uu);
      } else {
        f32x2 v; v[0]=hv[0]; v[1]=hv[1];
        *(f32x2*)(out + ((size_t)gb*TT + t)*HID + col0 + gc2) = v;
      }
      if (t < TT-1) {
        hdv0 = hv[0]*__expf(dtg1*ni0);
        hdv1 = hv[1]*__expf(dtg1*ni1);
        pk.h[0]=(f16)hdv0; pk.h[1]=(f16)hdv1;
        st_sc_u32((unsigned*)(HDl + (size_t)((t+1)&31)*65536 + slot), pk.uu);
      }
    }
    // ---- per-wave completion: drain own sc stores, bump WG counter
    asm volatile("s_waitcnt vmcnt(0)" ::: "memory");
    if (lane == 0) atom_inc_sc(flagOwn + (size_t)t*64 + wgl);
  }
}

extern "C" void kernel_launch(void* const* d_in, const int* in_sizes, int n_in,
                              void* d_out, int out_size, void* d_ws, size_t ws_size,
                              hipStream_t stream) {
  const float* x   = (const float*)d_in[0];
  const float* dtp = (const float*)d_in[1];
  const float* Wih = (const float*)d_in[2];
  const float* Whh = (const float*)d_in[3];
  const float* bih = (const float*)d_in[4];
  const float* bhh = (const float*)d_in[5];
  const float* tau = (const float*)d_in[6];
  float* out = (float*)d_out;
  char* ws = (char*)d_ws;

  // ws: xh [512][64][64][16] f16 (67,108,864) | H [3][512][65536] f16 (201,326,592)
  //   | HD [4][32][65536] f16 (16,777,216) | flags [4][512][64] u32 (524,288)
  //   -> total 285,736,960 B
  f16* xh = (f16*)ws;
  f16* H  = (f16*)(ws + 67108864);
  f16* HD = (f16*)(ws + 268435456);
  unsigned* flags = (unsigned*)(ws + 268435456 + 16777216);

  (void)hipMemsetAsync(flags, 0, 524288, stream);
  init_misc<<<16384, 256, 0, stream>>>(x, xh);
  const int ldsBytes = 139648;                      // PART + biases; >80KB -> 1 WG/CU
  (void)hipFuncSetAttribute((const void*)tsgru_k, hipFuncAttributeMaxDynamicSharedMemorySize, ldsBytes);
  tsgru_k<<<256, 512, ldsBytes, stream>>>(dtp, Wih, Whh, bih, bhh, tau, xh, H, HD, flags, out);
}

// Round 9
// 4519.992 us; speedup vs baseline: 1.5942x; 1.5942x over previous
//
#include <hip/hip_runtime.h>

typedef _Float16 f16;
typedef _Float16 half8 __attribute__((ext_vector_type(8)));
typedef float f32x4 __attribute__((ext_vector_type(4)));
typedef float f32x2 __attribute__((ext_vector_type(2)));

#define TT 512
#define HID 1024

__device__ __forceinline__ half8 cvt8(f32x4 lo, f32x4 hi) {
  half8 r;
  r[0]=(f16)lo[0]; r[1]=(f16)lo[1]; r[2]=(f16)lo[2]; r[3]=(f16)lo[3];
  r[4]=(f16)hi[0]; r[5]=(f16)hi[1]; r[6]=(f16)hi[2]; r[7]=(f16)hi[3];
  return r;
}
// device-scope coherent ops: write through / read past L2 (never flush caches)
__device__ __forceinline__ void st_sc_u32(unsigned* p, unsigned v) {
  asm volatile("global_store_dword %0, %1, off sc0 sc1" :: "v"(p), "v"(v) : "memory");
}
__device__ __forceinline__ unsigned ld_sc_u32(const unsigned* p) {
  unsigned v;
  asm volatile("global_load_dword %0, %1, off sc0 sc1\n\ts_waitcnt vmcnt(0)"
               : "=v"(v) : "v"(p) : "memory");
  return v;
}
// lane w polls its own padded (128B-strided) flag line -> no hot lines
__device__ __forceinline__ void pollPadded(const unsigned* base) {
  const unsigned* p = base + (size_t)(threadIdx.x & 63)*32;
  int gd = 0;
  while (__ballot(ld_sc_u32(p) == 0u)) {
    __builtin_amdgcn_s_sleep(1);
    if (++gd > (1<<20)) break;
  }
}
__device__ __forceinline__ void semSet(int* p, int v) {
  __hip_atomic_store(p, v, __ATOMIC_RELEASE, __HIP_MEMORY_SCOPE_WORKGROUP);
}
__device__ __forceinline__ void semWait(int* p, int v) {
  int gd = 0;
  while (__hip_atomic_load(p, __ATOMIC_ACQUIRE, __HIP_MEMORY_SCOPE_WORKGROUP) < v) {
    if (++gd > (1<<22)) break;
  }
}
__device__ __forceinline__ float sigm(float x)  { return 1.f/(1.f + __expf(-x)); }
__device__ __forceinline__ float ftanh(float x) { return 1.f - 2.f/(1.f + __expf(2.f*x)); }

// x [B][T][D] f32 -> xh [T][64 seg][64 b][16 c] f16 (WG-major plane layout)
__global__ void init_misc(const float* __restrict__ x, f16* __restrict__ xh) {
  size_t idx = (size_t)blockIdx.x*256 + threadIdx.x;
  size_t i = idx*8;
  int d = (int)(i & 1023);
  size_t bt = i >> 10;
  int t = (int)(bt & 511), b = (int)(bt >> 9);
  f32x4 a = *(const f32x4*)(x+i);
  f32x4 c4 = *(const f32x4*)(x+i+4);
  int s = d >> 4, c = d & 15;
  *(half8*)(xh + (((size_t)t*64 + s)*64 + b)*16 + c) = cvt8(a,c4);
}

// Persistent pipelined TSGRU. 256 WGs x 512 thr. WG = (layer, 16 cols),
// layer -> XCD pair. Waves 0-3: gx GEMM (upstream-gated); waves 4-7: gh GEMM
// (own-recurrence-gated) -- run in PARALLEL, so the recurrence chain contains
// only gh: detect -> hd load -> 96 MFMA -> dump -> bar -> gate -> drain -> flag.
// Wave (group g, kc): weights bW[3 gates][8 ks] for K-chunk kc*256, 96 VGPRs.
// Flags padded 128B/WG; one poller wave per dep + LDS semaphore release.
__global__ __launch_bounds__(512, 2) void tsgru_k(
    const float* __restrict__ dtp, const float* __restrict__ Wih,
    const float* __restrict__ Whh, const float* __restrict__ bih,
    const float* __restrict__ bhh, const float* __restrict__ tau,
    const f16* __restrict__ xh, f16* __restrict__ H, f16* __restrict__ HD,
    unsigned* __restrict__ flags, float* __restrict__ out) {
  extern __shared__ char lds[];
  float* PART  = (float*)lds;              // [8 wv][3 q][1088] f32 = 104448 B
  float* biasS = (float*)(lds + 104448);   // [6][16] f32
  int*   sem   = (int*)(lds + 104832);     // [2]

  const int tid = threadIdx.x, lane = tid & 63, wv = tid >> 6;
  const int g = wv >> 2, kc = wv & 3;
  const int bid = blockIdx.x;
  const int layer = (bid & 7) >> 1;                 // layer -> XCD pair
  const int wgl = (bid >> 3) | ((bid & 1) << 5);
  const int col0 = wgl * 16;
  const int u = (lane >> 4) & 3;

  // ---- persistent weights: this group's GEMM, K-chunk [kc*256, kc*256+256)
  const float* WL = (g ? Whh : Wih) + (size_t)layer*3072*HID;
  const int wcol = col0 + (lane & 15);
  half8 bW[3][8];
  #pragma unroll
  for (int q=0;q<3;q++)
    #pragma unroll
    for (int ks=0;ks<8;ks++) {
      const float* p = WL + (size_t)(q*HID + wcol)*HID + kc*256 + ks*32 + u*8;
      bW[q][ks] = cvt8(*(const f32x4*)p, *(const f32x4*)(p+4));
    }

  // ---- biases -> LDS; nitau + gate mapping in regs
  if (tid < 96) {
    int j = tid >> 4, c = tid & 15;
    biasS[tid] = (j < 3) ? bih[layer*3072 + j*HID + col0 + c]
                         : bhh[layer*3072 + (j-3)*HID + col0 + c];
  }
  if (tid < 2) sem[tid] = 0;
  const int gb = tid >> 3, gc2 = (tid & 7)*2;
  const float ni0 = -1.f/log1pf(expf(tau[layer*HID + col0 + gc2]));
  const float ni1 = -1.f/log1pf(expf(tau[layer*HID + col0 + gc2 + 1]));
  __syncthreads();

  // A-fragment base in WG-major plane [seg][b][16]: k = kc*256 + ks*32 + u*8
  const int baseA = (kc*16 + (u>>1))*1024 + (lane&15)*16 + (u&1)*8;
  const f16* gxBase = (layer==0) ? xh : H + (size_t)(layer-1)*TT*65536;
  f16* HDl = HD + (size_t)layer*32*65536;           // 32-plane rotation
  unsigned* flagOwn = flags + (size_t)layer*TT*64*32;
  const unsigned* flagUp = flags + (size_t)(layer>0 ? layer-1 : 0)*TT*64*32;

  float hdv0 = 0.f, hdv1 = 0.f;

  for (int t = 0; t < TT; ++t) {
    const float dtg1 = (t < TT-1) ? dtp[gb*TT + t + 1] : 0.f;

    f32x4 acc[4][3];
    #pragma unroll
    for (int m=0;m<4;m++) { acc[m][0]=(f32x4){0.f,0.f,0.f,0.f}; acc[m][1]=acc[m][0]; acc[m][2]=acc[m][0]; }

    if (g == 0) {
      // ======== gx group: gated by upstream[t] only ========
      if (wv == 0) {
        if (layer > 0) pollPadded(flagUp + (size_t)t*64*32);
        semSet(sem, t+1);
      } else {
        semWait(sem, t+1);
      }
      const f16* P = gxBase + (size_t)t*65536;
      half8 aF[3][4];
      #pragma unroll
      for (int c=0;c<3;c++)
        #pragma unroll
        for (int m=0;m<4;m++)
          aF[c][m] = *(const half8*)(P + baseA + c*2048 + m*256);
      #pragma unroll
      for (int ks=0;ks<8;ks++) {
        #pragma unroll
        for (int m=0;m<4;m++) {
          const half8 a = aF[ks%3][m];
          acc[m][0] = __builtin_amdgcn_mfma_f32_16x16x32_f16(a, bW[0][ks], acc[m][0],0,0,0);
          acc[m][1] = __builtin_amdgcn_mfma_f32_16x16x32_f16(a, bW[1][ks], acc[m][1],0,0,0);
          acc[m][2] = __builtin_amdgcn_mfma_f32_16x16x32_f16(a, bW[2][ks], acc[m][2],0,0,0);
        }
        if (ks < 5) {
          #pragma unroll
          for (int m=0;m<4;m++)
            aF[(ks+3)%3][m] = *(const half8*)(P + baseA + (ks+3)*2048 + m*256);
        }
      }
    } else {
      // ======== gh group: gated by own[t-1] (THE recurrence chain) ========
      if (wv == 4) {
        if (t > 0) pollPadded(flagOwn + (size_t)(t-1)*64*32);
        semSet(sem+1, t+1);
      } else {
        semWait(sem+1, t+1);
      }
      if (t > 0) {
        const f16* P = HDl + (size_t)(t & 31)*65536;
        half8 aF[3][4];
        #pragma unroll
        for (int c=0;c<3;c++)
          #pragma unroll
          for (int m=0;m<4;m++)
            aF[c][m] = *(const half8*)(P + baseA + c*2048 + m*256);
        #pragma unroll
        for (int ks=0;ks<8;ks++) {
          #pragma unroll
          for (int m=0;m<4;m++) {
            const half8 a = aF[ks%3][m];
            acc[m][0] = __builtin_amdgcn_mfma_f32_16x16x32_f16(a, bW[0][ks], acc[m][0],0,0,0);
            acc[m][1] = __builtin_amdgcn_mfma_f32_16x16x32_f16(a, bW[1][ks], acc[m][1],0,0,0);
            acc[m][2] = __builtin_amdgcn_mfma_f32_16x16x32_f16(a, bW[2][ks], acc[m][2],0,0,0);
          }
          if (ks < 5) {
            #pragma unroll
            for (int m=0;m<4;m++)
              aF[(ks+3)%3][m] = *(const half8*)(P + baseA + (ks+3)*2048 + m*256);
          }
        }
      }
    }

    // ---- dump: 3 slices/wave, col-major pad-68
    {
      float* Pb = PART + (size_t)(wv*3)*1088 + (lane&15)*68 + u*4;
      #pragma unroll
      for (int q=0;q<3;q++)
        #pragma unroll
        for (int m=0;m<4;m++)
          *(f32x4*)(Pb + q*1088 + m*16) = acc[m][q];
    }
    asm volatile("s_waitcnt lgkmcnt(0)" ::: "memory");
    __builtin_amdgcn_s_barrier();   // bar1: all partials published

    // ---- reduce + gate: thread -> (batch gb, cols gc2,gc2+1)
    {
      float hv[2];
      #pragma unroll
      for (int e=0;e<2;e++) {
        const int pb = (gc2+e)*68 + gb;
        float SX0=0.f,SX1=0.f,SX2=0.f,SH0=0.f,SH1=0.f,SH2=0.f;
        #pragma unroll
        for (int w=0;w<4;w++) {
          const float* Px = PART + (size_t)(w*3)*1088 + pb;
          SX0 += Px[0]; SX1 += Px[1088]; SX2 += Px[2176];
          const float* Ph = PART + (size_t)((4+w)*3)*1088 + pb;
          SH0 += Ph[0]; SH1 += Ph[1088]; SH2 += Ph[2176];
        }
        const float hdv = e ? hdv1 : hdv0;
        const float r = sigm(SX0 + biasS[gc2+e]    + SH0 + biasS[48+gc2+e]);
        const float z = sigm(SX1 + biasS[16+gc2+e] + SH1 + biasS[64+gc2+e]);
        const float n = ftanh(SX2 + biasS[32+gc2+e] + r*(SH2 + biasS[80+gc2+e]));
        hv[e] = (1.f - z)*n + z*hdv;
      }
      union { f16 h[2]; unsigned uu; } pk;
      const size_t slot = (size_t)(wgl*64 + gb)*16 + gc2;
      if (layer < 3) {
        pk.h[0]=(f16)hv[0]; pk.h[1]=(f16)hv[1];
        st_sc_u32((unsigned*)(H + ((size_t)layer*TT + t)*65536 + slot), pk.uu);
      } else {
        f32x2 v; v[0]=hv[0]; v[1]=hv[1];
        *(f32x2*)(out + ((size_t)gb*TT + t)*HID + col0 + gc2) = v;
      }
      if (t < TT-1) {
        hdv0 = hv[0]*__expf(dtg1*ni0);
        hdv1 = hv[1]*__expf(dtg1*ni1);
        pk.h[0]=(f16)hdv0; pk.h[1]=(f16)hdv1;
        st_sc_u32((unsigned*)(HDl + (size_t)((t+1)&31)*65536 + slot), pk.uu);
      }
    }
    asm volatile("s_waitcnt vmcnt(0)" ::: "memory");   // per-wave drain of sc stores
    __builtin_amdgcn_s_barrier();   // bar2: whole WG's state at coherent point
    if (tid == 0) st_sc_u32(flagOwn + ((size_t)t*64 + wgl)*32, 1u);
  }
}

extern "C" void kernel_launch(void* const* d_in, const int* in_sizes, int n_in,
                              void* d_out, int out_size, void* d_ws, size_t ws_size,
                              hipStream_t stream) {
  const float* x   = (const float*)d_in[0];
  const float* dtp = (const float*)d_in[1];
  const float* Wih = (const float*)d_in[2];
  const float* Whh = (const float*)d_in[3];
  const float* bih = (const float*)d_in[4];
  const float* bhh = (const float*)d_in[5];
  const float* tau = (const float*)d_in[6];
  float* out = (float*)d_out;
  char* ws = (char*)d_ws;

  // ws: xh 67,108,864 | H [3][512][65536] f16 201,326,592 | HD [4][32][65536] f16
  // 16,777,216 | flags [4][512][64][32] u32 16,777,216  -> total 301,989,888 B
  f16* xh = (f16*)ws;
  f16* H  = (f16*)(ws + 67108864);
  f16* HD = (f16*)(ws + 268435456);
  unsigned* flags = (unsigned*)(ws + 285212672);

  (void)hipMemsetAsync(flags, 0, 16777216, stream);
  init_misc<<<16384, 256, 0, stream>>>(x, xh);
  const int ldsBytes = 104960;                      // >80KB -> 1 WG/CU, grid=256=CUs
  (void)hipFuncSetAttribute((const void*)tsgru_k, hipFuncAttributeMaxDynamicSharedMemorySize, ldsBytes);
  tsgru_k<<<256, 512, ldsBytes, stream>>>(dtp, Wih, Whh, bih, bhh, tau, xh, H, HD, flags, out);
}